// Round 11
// baseline (135.466 us; speedup 1.0000x reference)
//
#include <hip/hip_runtime.h>
#include <hip/hip_fp16.h>

#define Nn 2048
#define Ff 64
#define Uu 64
#define NT 256
#define NCH 64          // chunks of 32 cols
#define G1S 68

typedef _Float16 f16x2 __attribute__((ext_vector_type(2)));
typedef _Float16 f16x8 __attribute__((ext_vector_type(8)));
typedef float    f32x4 __attribute__((ext_vector_type(4)));

#define MFMA32(a,b,c) __builtin_amdgcn_mfma_f32_16x16x32_f16(a,b,c,0,0,0)
#define GLD16(gp, lp) __builtin_amdgcn_global_load_lds(                      \
    (const __attribute__((address_space(1))) void*)(gp),                     \
    (__attribute__((address_space(3))) void*)(lp), 16, 0, 0)

// stage-buffer layout (bytes within one 20480B buffer)
#define OD0 0
#define OD1 2048
#define OG  4096
#define OK  6144
#define OW0 8192
#define OW1 14336
#define STG 20480
#define OP   40960     // P dbuf: [pc]{P0 1KB, P1 1KB}
#define OG1A 45056
#define OG1B 49408
#define OWS  53760     // 32 floats
#define OINV 53888     // 32 floats
#define SMSZ 54016

// ---- X transpose: Xt[b][f][k] = (f16) X[b][k][f] (validated R4-R10) ----
__global__ __launch_bounds__(256) void transposeX(const float* __restrict__ X,
                                                  _Float16* __restrict__ Xt) {
    __shared__ _Float16 tile[64][65];
    const int b = blockIdx.x, kt = blockIdx.y;
    #pragma unroll
    for (int i = 0; i < 16; ++i) {
        int e  = i * 256 + threadIdx.x;
        int kk = e >> 6, ff = e & 63;
        tile[ff][kk] = (_Float16)X[((size_t)b * Nn + kt * 64 + kk) * Ff + ff];
    }
    __syncthreads();
    #pragma unroll
    for (int i = 0; i < 16; ++i) {
        int e  = i * 256 + threadIdx.x;
        int ff = e >> 6, kk = e & 63;
        Xt[((size_t)b * Ff + ff) * Nn + kt * 64 + kk] = tile[ff][kk];
    }
}

// One block = 16 rows x 2 batches. Geo/KL staged ONCE per chunk and shared
// by both batches — cuts chip-wide requested bytes 790->660 MB. All staging
// via async global_load_lds (zero stage VGPRs); 5 loads per wave per chunk.
__global__ __launch_bounds__(NT, 2) void fused_gcn(
    const _Float16* __restrict__ Xt,  // [B,F,N] f16
    const float* __restrict__ Dyn,    // [B,N,N]
    const float* __restrict__ Wf,     // [B,N,N,3]
    const float* __restrict__ Geo,    // [N,N]
    const float* __restrict__ KLm,    // [N,N]
    const float* __restrict__ Wd,     // [F,U]
    const float* __restrict__ bdv,    // [U]
    float* __restrict__ out)          // [B,N,U]
{
    __shared__ __align__(16) char SM[SMSZ];

    const int t    = threadIdx.x;
    const int lane = t & 63;
    const int wid  = t >> 6;
    const int r    = lane & 15;
    const int kg   = lane >> 4;
    const int gidx = blockIdx.x & 127;
    const int p    = blockIdx.x >> 7;
    const int n0   = gidx << 4;
    const int b0   = p * 2, b1 = p * 2 + 1;

    const char* dyn0 = (const char*)(Dyn + ((size_t)b0 * Nn + n0) * Nn);
    const char* dyn1 = (const char*)(Dyn + ((size_t)b1 * Nn + n0) * Nn);
    const char* geo  = (const char*)(Geo + (size_t)n0 * Nn);
    const char* klm  = (const char*)(KLm + (size_t)n0 * Nn);
    const char* wf0  = (const char*)(Wf + ((size_t)b0 * Nn + n0) * (size_t)Nn * 3);
    const char* wf1  = (const char*)(Wf + ((size_t)b1 * Nn + n0) * (size_t)Nn * 3);

    // D-type per-lane offsets: rows h*8+(lane>>3), 16B within 128B row-chunk
    const size_t dA = (size_t)(lane >> 3) * (Nn * 4) + (size_t)(lane & 7) * 16;
    const size_t dB = dA + (size_t)8 * (Nn * 4);
    // W per-lane offset for slot j: linear L=j*1024+lane*16 -> row L/384, off L%384
#define WL(j) ((size_t)(((j)*1024 + lane*16) / 384) * (Nn*12) + (size_t)(((j)*1024 + lane*16) % 384))

    // 20 loads/chunk distributed 5 per wave (named regs, no runtime-idx arrays)
    const char *s0, *s1, *s2, *s3, *s4;
    int l0, l1, l2, l3, l4, i0, i1, i2, i3, i4;
    if (wid == 0) {
        s0 = dyn0 + dA;   l0 = OD0;        i0 = 128;
        s1 = dyn0 + dB;   l1 = OD0 + 1024; i1 = 128;
        s2 = dyn1 + dA;   l2 = OD1;        i2 = 128;
        s3 = dyn1 + dB;   l3 = OD1 + 1024; i3 = 128;
        s4 = geo  + dA;   l4 = OG;         i4 = 128;
    } else if (wid == 1) {
        s0 = geo + dB;    l0 = OG + 1024;  i0 = 128;
        s1 = klm + dA;    l1 = OK;         i1 = 128;
        s2 = klm + dB;    l2 = OK + 1024;  i2 = 128;
        s3 = wf0 + WL(0); l3 = OW0;        i3 = 384;
        s4 = wf0 + WL(1); l4 = OW0 + 1024; i4 = 384;
    } else if (wid == 2) {
        s0 = wf0 + WL(2); l0 = OW0 + 2048; i0 = 384;
        s1 = wf0 + WL(3); l1 = OW0 + 3072; i1 = 384;
        s2 = wf0 + WL(4); l2 = OW0 + 4096; i2 = 384;
        s3 = wf0 + WL(5); l3 = OW0 + 5120; i3 = 384;
        s4 = wf1 + WL(0); l4 = OW1;        i4 = 384;
    } else {
        s0 = wf1 + WL(1); l0 = OW1 + 1024; i0 = 384;
        s1 = wf1 + WL(2); l1 = OW1 + 2048; i1 = 384;
        s2 = wf1 + WL(3); l2 = OW1 + 3072; i2 = 384;
        s3 = wf1 + WL(4); l3 = OW1 + 4096; i3 = 384;
        s4 = wf1 + WL(5); l4 = OW1 + 5120; i4 = 384;
    }

#define STAGE(P) { char* _b = SM + (P) * STG;                         \
    GLD16(s0, _b + l0); GLD16(s1, _b + l1); GLD16(s2, _b + l2);       \
    GLD16(s3, _b + l3); GLD16(s4, _b + l4);                           \
    s0 += i0; s1 += i1; s2 += i2; s3 += i3; s4 += i4; }

    const _Float16* xw0 = Xt + (size_t)b0 * Ff * Nn
                        + (size_t)(wid * 16 + r) * Nn + (kg << 3);
    const _Float16* xw1 = Xt + (size_t)b1 * Ff * Nn
                        + (size_t)(wid * 16 + r) * Nn + (kg << 3);

    const int e = t >> 4, q = t & 15;       // exp-pass: row e, col-pair q
    f32x4 acc0 = {0.f,0.f,0.f,0.f}, acc1 = {0.f,0.f,0.f,0.f};
    float rs0 = 0.f, rs1 = 0.f;

    STAGE(0);
    asm volatile("s_waitcnt vmcnt(0)" ::: "memory");
    __builtin_amdgcn_s_barrier();

    #pragma unroll 1
    for (int c = 0; c < NCH; ++c) {
        const int pc = c & 1;

        // B-frags first (oldest vmcnt entries: their waits never drain stage)
        f16x8 bf0 = *(const f16x8*)xw0;
        f16x8 bf1 = *(const f16x8*)xw1;
        xw0 += 32; xw1 += 32;
        __builtin_amdgcn_sched_barrier(0);
        if (c + 1 < NCH) STAGE(pc ^ 1);
        __builtin_amdgcn_sched_barrier(0);

        // ---- exp-pass on staged chunk c (LDS in, swizzled f16 P out) ----
        {
            const char* st = SM + pc * STG;
            const float* Dc0 = (const float*)(st + OD0);
            const float* Dc1 = (const float*)(st + OD1);
            const float* Gc  = (const float*)(st + OG);
            const float* Kc  = (const float*)(st + OK);
            const float* Wc0 = (const float*)(st + OW0);
            const float* Wc1 = (const float*)(st + OW1);
            float2 gv = *(const float2*)(Gc + e * 32 + q * 2);
            float2 kv = *(const float2*)(Kc + e * 32 + q * 2);
            float2 d0 = *(const float2*)(Dc0 + e * 32 + q * 2);
            float2 d1 = *(const float2*)(Dc1 + e * 32 + q * 2);
            float2 wa0 = *(const float2*)(Wc0 + e * 96 + q * 6);
            float2 wb0 = *(const float2*)(Wc0 + e * 96 + q * 6 + 2);
            float2 wc0 = *(const float2*)(Wc0 + e * 96 + q * 6 + 4);
            float2 wa1 = *(const float2*)(Wc1 + e * 96 + q * 6);
            float2 wb1 = *(const float2*)(Wc1 + e * 96 + q * 6 + 2);
            float2 wc1 = *(const float2*)(Wc1 + e * 96 + q * 6 + 4);
            float e00 = __expf(fminf(d0.x*wa0.x + gv.x*wa0.y + kv.x*wb0.x, 11.f));
            float e01 = __expf(fminf(d0.y*wb0.y + gv.y*wc0.x + kv.y*wc0.y, 11.f));
            float e10 = __expf(fminf(d1.x*wa1.x + gv.x*wa1.y + kv.x*wb1.x, 11.f));
            float e11 = __expf(fminf(d1.y*wb1.y + gv.y*wc1.x + kv.y*wc1.y, 11.f));
            _Float16 h00 = (_Float16)e00, h01 = (_Float16)e01;
            _Float16 h10 = (_Float16)e10, h11 = (_Float16)e11;
            rs0 += (float)h00 + (float)h01;
            rs1 += (float)h10 + (float)h11;
            char* Pb = SM + OP + pc * 2048;
            const int pa = (e * 64 + q * 4) ^ ((e & 7) << 4);
            f16x2 v0 = {h00, h01}, v1 = {h10, h11};
            *(f16x2*)(Pb + pa) = v0;
            *(f16x2*)(Pb + 1024 + pa) = v1;
        }
        asm volatile("s_waitcnt lgkmcnt(0)" ::: "memory");
        __builtin_amdgcn_sched_barrier(0);
        __builtin_amdgcn_s_barrier();

        // ---- MFMA: A from swizzled P (per batch), B from L2 Xt ----
        {
            const char* Pc = SM + OP + pc * 2048;
            const int ao = (r * 64 + kg * 16) ^ ((r & 7) << 4);
            f16x8 af0 = *(const f16x8*)(Pc + ao);
            f16x8 af1 = *(const f16x8*)(Pc + 1024 + ao);
            acc0 = MFMA32(af0, bf0, acc0);
            acc1 = MFMA32(af1, bf1, acc1);
        }
        asm volatile("s_waitcnt vmcnt(0)" ::: "memory");
        __builtin_amdgcn_sched_barrier(0);
        __builtin_amdgcn_s_barrier();
    }

    // ---- row sums (row = wid*4 + (lane>>4), 16-lane groups) ----
    float v0 = rs0, v1 = rs1;
    v0 += __shfl_xor(v0, 1, 64); v0 += __shfl_xor(v0, 2, 64);
    v0 += __shfl_xor(v0, 4, 64); v0 += __shfl_xor(v0, 8, 64);
    v1 += __shfl_xor(v1, 1, 64); v1 += __shfl_xor(v1, 2, 64);
    v1 += __shfl_xor(v1, 4, 64); v1 += __shfl_xor(v1, 8, 64);
    float* ws = (float*)(SM + OWS);
    if ((lane & 15) == 0) {
        ws[(wid << 2) + (lane >> 4)] = v0;
        ws[16 + (wid << 2) + (lane >> 4)] = v1;
    }
    __syncthreads();
    float* inv = (float*)(SM + OINV);
    if (t < 32) inv[t] = 1.0f / ws[t];
    __syncthreads();

    // ---- normalized G1 tiles (C layout validated R6/R10) ----
    float* g1a = (float*)(SM + OG1A);
    float* g1b = (float*)(SM + OG1B);
    #pragma unroll
    for (int i = 0; i < 4; ++i) {
        const int ro = (kg << 2) + i;
        g1a[ro * G1S + (wid << 4) + r] = acc0[i] * inv[ro];
        g1b[ro * G1S + (wid << 4) + r] = acc1[i] * inv[16 + ro];
    }
    __syncthreads();

    // ---- Dense(64) + tanh for both batches ----
    const int row0 = wid << 2;
    const float* ga = g1a + row0 * G1S;
    const float* gb = g1b + row0 * G1S;
    float bb = bdv[lane];
    float a0 = bb, a1 = bb, a2 = bb, a3 = bb;
    float c0 = bb, c1 = bb, c2 = bb, c3 = bb;
    #pragma unroll 4
    for (int f = 0; f < Ff; ++f) {
        float wdv = Wd[f * Uu + lane];
        a0 += ga[f] * wdv;           a1 += ga[G1S + f] * wdv;
        a2 += ga[2 * G1S + f] * wdv; a3 += ga[3 * G1S + f] * wdv;
        c0 += gb[f] * wdv;           c1 += gb[G1S + f] * wdv;
        c2 += gb[2 * G1S + f] * wdv; c3 += gb[3 * G1S + f] * wdv;
    }
    float oa[4] = {a0, a1, a2, a3}, ob[4] = {c0, c1, c2, c3};
    #pragma unroll
    for (int i = 0; i < 4; ++i) {
        float x  = fminf(fmaxf(oa[i], -15.f), 15.f);
        float ex = __expf(2.f * x);
        out[((size_t)b0 * Nn + n0 + row0 + i) * Uu + lane] = (ex - 1.f) / (ex + 1.f);
        float y  = fminf(fmaxf(ob[i], -15.f), 15.f);
        float ey = __expf(2.f * y);
        out[((size_t)b1 * Nn + n0 + row0 + i) * Uu + lane] = (ey - 1.f) / (ey + 1.f);
    }
}

extern "C" void kernel_launch(void* const* d_in, const int* in_sizes, int n_in,
                              void* d_out, int out_size, void* d_ws, size_t ws_size,
                              hipStream_t stream) {
    const float* X   = (const float*)d_in[0];
    const float* Dyn = (const float*)d_in[1];
    const float* Wf  = (const float*)d_in[2];
    const float* Geo = (const float*)d_in[3];
    const float* KLm = (const float*)d_in[4];
    const float* Wd  = (const float*)d_in[5];
    const float* bdv = (const float*)d_in[6];
    float* out = (float*)d_out;

    _Float16* Xt = (_Float16*)d_ws;   // 2 MB scratch
    transposeX<<<dim3(8, Nn / 64), dim3(256), 0, stream>>>(X, Xt);
    fused_gcn<<<dim3(4 * 128), dim3(NT), 0, stream>>>(
        Xt, Dyn, Wf, Geo, KLm, Wd, bdv, out);
}